// Round 4
// baseline (1235.262 us; speedup 1.0000x reference)
//
#include <hip/hip_runtime.h>
#include <math.h>

#define TTOK 8192
#define DDIM 1024
#define HDIM 4096
#define NEXP 8
#define NASSIGN (TTOK * 2)

typedef float f32x4 __attribute__((ext_vector_type(4)));
typedef short s16x8 __attribute__((ext_vector_type(8)));

__device__ __forceinline__ unsigned short f2bf(float f) {
  union { float f; unsigned int u; } v; v.f = f;
  unsigned int u = v.u;
  u += 0x7FFFu + ((u >> 16) & 1u);   // RNE
  return (unsigned short)(u >> 16);
}

__device__ __forceinline__ s16x8 f2bf8(float4 a, float4 b) {
  s16x8 o;
  o[0] = (short)f2bf(a.x); o[1] = (short)f2bf(a.y);
  o[2] = (short)f2bf(a.z); o[3] = (short)f2bf(a.w);
  o[4] = (short)f2bf(b.x); o[5] = (short)f2bf(b.y);
  o[6] = (short)f2bf(b.z); o[7] = (short)f2bf(b.w);
  return o;
}

// gelu_tanh(x) = 0.5x(1+tanh(u)) = x * sigmoid(2u),  u = sqrt(2/pi)(x+0.044715x^3)
__device__ __forceinline__ float gelu_fast(float x) {
  float u = 0.7978845608028654f * x * (1.0f + 0.044715f * x * x);
  return x / (1.0f + __expf(-2.0f * u));
}

// ---- fp32 -> bf16 conversion, both weight tensors, 32B read / 16B write per thread ----
__global__ void cvt_bf16_k(const float* __restrict__ w1, unsigned short* __restrict__ w1b,
                           const float* __restrict__ w2, unsigned short* __restrict__ w2b,
                           int n8) {  // n8 = 8-float units per tensor
  int i = blockIdx.x * blockDim.x + threadIdx.x;
  const float* src; unsigned short* dst;
  if (i < n8) { src = w1; dst = w1b; } else { src = w2; dst = w2b; i -= n8; }
  float4 a = ((const float4*)src)[2 * i];
  float4 b = ((const float4*)src)[2 * i + 1];
  ((s16x8*)dst)[i] = f2bf8(a, b);
}

// ---- router: logits = (x + se[sidx]) @ rw^T + rb ; top-2 + softmax (fp64 acc) ----
__global__ void router_k(const float* __restrict__ x, const float* __restrict__ se,
                         const int* __restrict__ sidx, const float* __restrict__ rw,
                         const float* __restrict__ rb,
                         int* __restrict__ e0, int* __restrict__ e1,
                         float* __restrict__ w0, float* __restrict__ w1,
                         int* __restrict__ counts) {
  int t = blockIdx.x * 4 + (threadIdx.x >> 6);
  int lane = threadIdx.x & 63;
  const float4* xp = (const float4*)(x + (size_t)t * DDIM) + lane * 4;
  const float4* sp = (const float4*)(se + (size_t)sidx[0] * DDIM) + lane * 4;
  float xs[16];
#pragma unroll
  for (int c = 0; c < 4; ++c) {
    float4 a = xp[c], b = sp[c];
    xs[c * 4 + 0] = a.x + b.x; xs[c * 4 + 1] = a.y + b.y;
    xs[c * 4 + 2] = a.z + b.z; xs[c * 4 + 3] = a.w + b.w;
  }
  double acc[NEXP];
#pragma unroll
  for (int e = 0; e < NEXP; ++e) acc[e] = 0.0;
#pragma unroll
  for (int e = 0; e < NEXP; ++e) {
    const float4* wp = (const float4*)(rw + (size_t)e * DDIM) + lane * 4;
#pragma unroll
    for (int c = 0; c < 4; ++c) {
      float4 wv = wp[c];
      acc[e] += (double)xs[c * 4 + 0] * wv.x + (double)xs[c * 4 + 1] * wv.y +
                (double)xs[c * 4 + 2] * wv.z + (double)xs[c * 4 + 3] * wv.w;
    }
  }
#pragma unroll
  for (int e = 0; e < NEXP; ++e) {
#pragma unroll
    for (int m = 32; m >= 1; m >>= 1) acc[e] += __shfl_xor(acc[e], m, 64);
  }
  if (lane == 0) {
    float lg[NEXP];
    for (int e = 0; e < NEXP; ++e) lg[e] = (float)acc[e] + rb[e];
    int i0 = 0; float l0 = lg[0];
    for (int e = 1; e < NEXP; ++e) if (lg[e] > l0) { l0 = lg[e]; i0 = e; }
    int i1 = -1; float l1 = -1e30f;
    for (int e = 0; e < NEXP; ++e) if (e != i0 && lg[e] > l1) { l1 = lg[e]; i1 = e; }
    float z = expf(l1 - l0);
    float p0 = 1.0f / (1.0f + z);
    e0[t] = i0; e1[t] = i1; w0[t] = p0; w1[t] = 1.0f - p0;
    atomicAdd(&counts[i0], 1);
    atomicAdd(&counts[i1], 1);
  }
}

// prefix-scan + build m-tile table (<=136 entries of {m0, row1, e, 0})
__global__ void scan_k(const int* __restrict__ counts, int* __restrict__ offsets,
                       int* __restrict__ cursors, int4* __restrict__ tileT,
                       int* __restrict__ ntiles) {
  if (threadIdx.x == 0 && blockIdx.x == 0) {
    int s = 0;
    for (int e = 0; e < NEXP; ++e) { offsets[e] = s; cursors[e] = s; s += counts[e]; }
    offsets[NEXP] = s;
    int nt = 0;
    for (int e = 0; e < NEXP; ++e)
      for (int m0 = offsets[e]; m0 < offsets[e + 1]; m0 += 128)
        tileT[nt++] = make_int4(m0, offsets[e + 1], e, 0);
    ntiles[0] = nt;
  }
}

// fused scatter + gather: block per token; assigns 2 slots, writes bf16 x-row to both
__global__ void sg_k(const float* __restrict__ x, const int* __restrict__ e0,
                     const int* __restrict__ e1, int* __restrict__ cursors,
                     int* __restrict__ s0, int* __restrict__ s1,
                     unsigned short* __restrict__ Xg) {
  __shared__ int sp0, sp1;
  const int t = blockIdx.x;
  const int i = threadIdx.x;   // 0..127
  if (i == 0) {
    int p = atomicAdd(&cursors[e0[t]], 1);
    sp0 = p; s0[t] = p;
    p = atomicAdd(&cursors[e1[t]], 1);
    sp1 = p; s1[t] = p;
  }
  float4 a = ((const float4*)(x + (size_t)t * DDIM))[2 * i];
  float4 b = ((const float4*)(x + (size_t)t * DDIM))[2 * i + 1];
  s16x8 o = f2bf8(a, b);
  __syncthreads();
  ((s16x8*)(Xg + (size_t)sp0 * DDIM))[i] = o;
  ((s16x8*)(Xg + (size_t)sp1 * DDIM))[i] = o;
}

// ---- persistent grouped NT GEMM, 128x128 tile, BK=32 DOUBLE-BUFFERED (32 KB LDS) ----
// XOR-swizzled LDS (bank-optimal); loads for stage kt+1 issued right after the
// barrier, drained at the NEXT barrier -> one full compute iteration in flight.
// EPI==0: fc1 -> gelu -> bf16 Hout.   EPI==1: fc2 -> (+bias) -> f32 rows in Yout.
template <int KD, int ND, int EPI>
__global__ __launch_bounds__(256) void moe_gemm_k(
    const unsigned short* __restrict__ A,   // compacted slots x KD (bf16)
    const unsigned short* __restrict__ W,   // NEXP x ND x KD (bf16)
    const float* __restrict__ bias,         // NEXP x ND
    const int4* __restrict__ tileT, const int* __restrict__ ntiles,
    unsigned short* __restrict__ Hout, float* __restrict__ Yout) {
  constexpr int NT = ND / 128;
  constexpr int G = NT / 8;                  // n-blocks per XCD
  constexpr int NK = KD / 32;
  __shared__ unsigned short As[2][128 * 32];
  __shared__ unsigned short Bs[2][128 * 32];

  const int tid = threadIdx.x;
  const int lane = tid & 63;
  const int w = tid >> 6;
  const int q = lane >> 4;       // k-chunk for fragment read
  const int c16 = lane & 15;
  const int cxx = c16 & 3;       // read-side swizzle key (row&3)
  const int wrow = (w >> 1) * 64;
  const int wcol = (w & 1) * 64;
  const int grow = tid >> 2;                 // staging row 0..63 within issue group
  const int gchunk = (tid & 3) ^ (grow & 3); // swizzled global 16B-chunk

  const int xcd = blockIdx.x & 7;
  const int lid = blockIdx.x >> 3;           // 0..255 within XCD group
  const int bound = ntiles[0] * G;           // uniform across block

  for (int idx = lid; idx < bound; idx += 256) {
    const int mt = idx / G;
    const int nb = xcd * G + (idx - mt * G);
    const int4 tl = tileT[mt];
    const int m0 = tl.x, row1 = tl.y, e = tl.z;
    const int n0 = nb * 128;
    const unsigned short* We = W + (size_t)e * ND * KD;

    const unsigned short* aptr[2];
    const unsigned short* bptr[2];
#pragma unroll
    for (int ig = 0; ig < 2; ++ig) {
      int ar = m0 + ig * 64 + grow;
      if (ar > row1 - 1) ar = row1 - 1;  // clamp: garbage rows masked at store
      aptr[ig] = A + (size_t)ar * KD + gchunk * 8;
      bptr[ig] = We + (size_t)(n0 + ig * 64 + grow) * KD + gchunk * 8;
    }

    f32x4 acc[4][4];
#pragma unroll
    for (int i = 0; i < 4; ++i)
#pragma unroll
      for (int j = 0; j < 4; ++j) acc[i][j] = {0.f, 0.f, 0.f, 0.f};

    __syncthreads();   // previous tile's readers done before overwriting stage 0

#define LOAD_STAGE(buf, k0)                                                        \
    {                                                                              \
      _Pragma("unroll")                                                            \
      for (int ig = 0; ig < 2; ++ig) {                                             \
        __builtin_amdgcn_global_load_lds(                                          \
            (const __attribute__((address_space(1))) void*)(aptr[ig] + (k0)),      \
            (__attribute__((address_space(3))) void*)(&As[buf][(ig * 64 + w * 16) * 32]), \
            16, 0, 0);                                                             \
        __builtin_amdgcn_global_load_lds(                                          \
            (const __attribute__((address_space(1))) void*)(bptr[ig] + (k0)),      \
            (__attribute__((address_space(3))) void*)(&Bs[buf][(ig * 64 + w * 16) * 32]), \
            16, 0, 0);                                                             \
      }                                                                            \
    }

    LOAD_STAGE(0, 0);

    for (int kt = 0; kt < NK; ++kt) {
      __syncthreads();                       // drains stage kt loads (1 iter in flight)
      if (kt + 1 < NK) LOAD_STAGE((kt + 1) & 1, (kt + 1) * 32);
      const int buf = kt & 1;
      s16x8 af[4], bv[4];
#pragma unroll
      for (int i = 0; i < 4; ++i)
        af[i] = *((const s16x8*)(&As[buf][(wrow + i * 16 + c16) * 32 + (q ^ cxx) * 8]));
#pragma unroll
      for (int j = 0; j < 4; ++j)
        bv[j] = *((const s16x8*)(&Bs[buf][(wcol + j * 16 + c16) * 32 + (q ^ cxx) * 8]));
#pragma unroll
      for (int i = 0; i < 4; ++i)
#pragma unroll
        for (int j = 0; j < 4; ++j)
          acc[i][j] = __builtin_amdgcn_mfma_f32_16x16x32_bf16(af[i], bv[j], acc[i][j], 0, 0, 0);
    }
#undef LOAD_STAGE

    // epilogue: C/D layout col=lane&15, row=(lane>>4)*4+reg  [m89/m91-verified]
    float bj[4];
#pragma unroll
    for (int j = 0; j < 4; ++j)
      bj[j] = bias[(size_t)e * ND + n0 + wcol + j * 16 + c16];
#pragma unroll
    for (int i = 0; i < 4; ++i) {
#pragma unroll
      for (int r = 0; r < 4; ++r) {
        const int m = m0 + wrow + i * 16 + q * 4 + r;
        if (m < row1) {
          if (EPI == 0) {
#pragma unroll
            for (int j = 0; j < 4; ++j) {
              const int n = n0 + wcol + j * 16 + c16;
              Hout[(size_t)m * ND + n] = f2bf(gelu_fast(acc[i][j][r] + bj[j]));
            }
          } else {
#pragma unroll
            for (int j = 0; j < 4; ++j) {
              const int n = n0 + wcol + j * 16 + c16;
              Yout[(size_t)m * ND + n] = acc[i][j][r] + bj[j];
            }
          }
        }
      }
    }
  }
}

// out[t] = w0[t]*Yr[s0[t]] + w1[t]*Yr[s1[t]]   (block per token, 128 thr, 32B/thr)
__global__ void combine_k(const float* __restrict__ Yr, const int* __restrict__ s0,
                          const int* __restrict__ s1, const float* __restrict__ tw0,
                          const float* __restrict__ tw1, float* __restrict__ out) {
  const int t = blockIdx.x;
  const int i = threadIdx.x;   // 0..127
  const int a = s0[t], b = s1[t];
  const float wa = tw0[t], wb = tw1[t];
  const float4* pa = (const float4*)(Yr + (size_t)a * DDIM);
  const float4* pb = (const float4*)(Yr + (size_t)b * DDIM);
  float4* po = (float4*)(out + (size_t)t * DDIM);
#pragma unroll
  for (int c = 0; c < 2; ++c) {
    float4 va = pa[2 * i + c], vb = pb[2 * i + c];
    float4 o;
    o.x = wa * va.x + wb * vb.x;
    o.y = wa * va.y + wb * vb.y;
    o.z = wa * va.z + wb * vb.z;
    o.w = wa * va.w + wb * vb.w;
    po[2 * i + c] = o;
  }
}

extern "C" void kernel_launch(void* const* d_in, const int* in_sizes, int n_in,
                              void* d_out, int out_size, void* d_ws, size_t ws_size,
                              hipStream_t stream) {
  const float* x  = (const float*)d_in[0];
  const float* se = (const float*)d_in[1];
  const float* rw = (const float*)d_in[2];
  const float* rb = (const float*)d_in[3];
  const float* w1 = (const float*)d_in[4];
  const float* b1 = (const float*)d_in[5];
  const float* w2 = (const float*)d_in[6];
  const float* b2 = (const float*)d_in[7];
  const int* sidx = (const int*)d_in[8];
  float* out = (float*)d_out;

  char* ws = (char*)d_ws;
  size_t off = 0;
  unsigned short* w1b = (unsigned short*)(ws + off); off += (size_t)NEXP * HDIM * DDIM * 2;  // 64 MB
  unsigned short* w2b = (unsigned short*)(ws + off); off += (size_t)NEXP * DDIM * HDIM * 2;  // 64 MB
  unsigned short* Xg  = (unsigned short*)(ws + off); off += (size_t)NASSIGN * DDIM * 2;      // 32 MB
  unsigned short* Hb  = (unsigned short*)(ws + off); off += (size_t)NASSIGN * HDIM * 2;      // 128 MB
  float* Yr = (float*)w1b;  // 64 MB, overlays w1b (dead after fc1)
  int*   counts  = (int*)(ws + off); off += 64;
  int*   offsets = (int*)(ws + off); off += 64;
  int*   cursors = (int*)(ws + off); off += 64;
  int*   ntiles  = (int*)(ws + off); off += 64;
  int*   e0  = (int*)(ws + off);   off += (size_t)TTOK * 4;
  int*   e1  = (int*)(ws + off);   off += (size_t)TTOK * 4;
  float* tw0 = (float*)(ws + off); off += (size_t)TTOK * 4;
  float* tw1 = (float*)(ws + off); off += (size_t)TTOK * 4;
  int*   s0  = (int*)(ws + off);   off += (size_t)TTOK * 4;
  int*   s1  = (int*)(ws + off);   off += (size_t)TTOK * 4;
  int4*  tileT = (int4*)(ws + off);  off += 256 * 16;

  hipMemsetAsync(counts, 0, 64, stream);

  const int n8 = NEXP * HDIM * DDIM / 8;
  cvt_bf16_k<<<2 * n8 / 256, 256, 0, stream>>>(w1, w1b, w2, w2b, n8);
  router_k<<<TTOK / 4, 256, 0, stream>>>(x, se, sidx, rw, rb, e0, e1, tw0, tw1, counts);
  scan_k<<<1, 64, 0, stream>>>(counts, offsets, cursors, tileT, ntiles);
  sg_k<<<TTOK, 128, 0, stream>>>(x, e0, e1, cursors, s0, s1, Xg);

  moe_gemm_k<DDIM, HDIM, 0><<<2048, 256, 0, stream>>>(Xg, w1b, b1, tileT, ntiles, Hb, Yr);
  moe_gemm_k<HDIM, DDIM, 1><<<2048, 256, 0, stream>>>(Hb, w2b, b2, tileT, ntiles, Hb, Yr);
  combine_k<<<TTOK, 128, 0, stream>>>(Yr, s0, s1, tw0, tw1, out);
}